// Round 9
// baseline (1219.567 us; speedup 1.0000x reference)
//
#include <hip/hip_runtime.h>
#include <math.h>
#include <stdint.h>

#define D       128
#define KCODES  1024
#define NQ      8
#define BATCH   8
#define SLEN    4096
#define NPTS    (BATCH*SLEN)     /* 32768 */
#define TM      64               /* points per argmin unit */

// async global->LDS, 16B per lane (wave-uniform LDS base + lane*16)
typedef __attribute__((address_space(1))) const void GV;
typedef __attribute__((address_space(3))) void LV;
__device__ __forceinline__ void gload16(const void* g, void* l) {
    __builtin_amdgcn_global_load_lds((GV*)g, (LV*)l, 16, 0, 0);
}

// ---------------- zero scratch ----------------
__global__ void k_zero(int* hist, double* csum) {
    int t = blockIdx.x * blockDim.x + threadIdx.x;
    if (t < NQ * KCODES) hist[t] = 0;
    if (t == 0) *csum = 0.0;
}

// ---------------- codebook norms: numpy pairwise fp32 ----------------
__global__ void k_c2(const float* __restrict__ cbs, float* __restrict__ c2f) {
    int i = blockIdx.x * blockDim.x + threadIdx.x;   // 0..8191
    const float* row = cbs + (size_t)i * D;
    float r8[8];
    #pragma unroll
    for (int j = 0; j < 8; ++j) r8[j] = __fmul_rn(row[j], row[j]);
    for (int d = 8; d < 128; d += 8)
        #pragma unroll
        for (int j = 0; j < 8; ++j)
            r8[j] = __fadd_rn(r8[j], __fmul_rn(row[d + j], row[d + j]));
    float s01 = __fadd_rn(r8[0], r8[1]);
    float s23 = __fadd_rn(r8[2], r8[3]);
    float s45 = __fadd_rn(r8[4], r8[5]);
    float s67 = __fadd_rn(r8[6], r8[7]);
    c2f[i] = __fadd_rn(__fadd_rn(s01, s23), __fadd_rn(s45, s67));
}

// ---------------- init: z [B,D,S] -> resid fp32 [n][d]; quant = 0 ----------------
__global__ __launch_bounds__(256) void k_init(const float* __restrict__ z,
                                              float* __restrict__ resid,
                                              float* __restrict__ quant) {
    __shared__ float xt[64][129];
    int b = blockIdx.x >> 6, st = blockIdx.x & 63;
    int s0 = st * 64;
    for (int it = 0; it < 32; ++it) {
        int flat = it * 256 + threadIdx.x;
        int d = flat >> 6, sl = flat & 63;
        xt[sl][d] = z[((size_t)(b * D + d)) * SLEN + s0 + sl];
    }
    __syncthreads();
    for (int it = 0; it < 8; ++it) {
        int flat = it * 256 + threadIdx.x;
        int sl = flat >> 5, dq = (flat & 31) * 4;
        size_t o = (size_t)(b * SLEN + s0 + sl) * D + dq;
        float4 r;
        r.x = xt[sl][dq]; r.y = xt[sl][dq + 1];
        r.z = xt[sl][dq + 2]; r.w = xt[sl][dq + 3];
        *(float4*)(resid + o) = r;
        float4 zz; zz.x = zz.y = zz.z = zz.w = 0.0f;
        *(float4*)(quant + o) = zz;
    }
}

// ---------------- fp32-emulated argmin (matches numpy/BLAS rounding) ----------------
// r9: attack the AGPR copy tax. r7/r8 both sat at 140us with VALU-time
// 104us vs 54.6us FMA floor: accs live in AGPRs (r8: 84 arch VGPR for a
// 64-acc kernel) and each 4-FMA acc touch pays accvgpr_read+write = +50%
// VALU. Fix: PAIR-STEP -- process two consecutive 4-dim slices per step
// with an explicit RMW temp, so each acc is touched once per 8 FMAs
// (+25% tax). 4-buffer ring (even pair -> bufs 0/1, odd -> 2/3), pair
// P+1 issued then vmcnt(2): one pair in flight, 2x r8's latency cover,
// no buffer collision. Geometry/occupancy as r7/r8 (3 blocks/CU at
// LDS 54,272; grid 1024 = 512 pblk x 2 halves; fused merge in k_update).
// Exact fp32 semantics preserved: per (point,code) single FMA chain,
// dims 0..127 ascending (slice A's 4 dims then slice B's, slices asc);
// score fl(fl(xx-2*acc)+cc); first-min (strict <, k ascending; lex
// (score,k) reduce; cross-half merge tie -> lower half).
__global__ __launch_bounds__(256) void k_argmin(const float* __restrict__ cb,
                                                const float* __restrict__ c2,
                                                const float* __restrict__ resid,
                                                float* __restrict__ pbest,
                                                int* __restrict__ pidx) {
    __shared__ __align__(16) float xs[TM][132];       // 33,792 B (xx in col 128)
    __shared__ __align__(16) float cs[4][4][256];     // 16,384 B: [wave][4buf][64c x 4d]
    __shared__ __align__(16) float ccl[4][128];       //  2,048 B: per-wave c2
    __shared__ float redS[4][TM];                     //  1,024 B
    __shared__ int   redI[4][TM];                     //  1,024 B

    int tid = threadIdx.x;
    int u = blockIdx.x;
    int pblk = u >> 1, half = u & 1;
    int pbase = pblk * TM;
    int l = tid & 63, w = tid >> 6;
    int pl = l & 7, cl = l >> 3;

    // wave's 128 code rows (512 B each)
    const char* cwb = (const char*)cb + ((size_t)(half * 512 + w * 128) << 9);
    char* csw = (char*)&cs[w][0][0];
    const char* xsb = (const char*)&xs[0][0];

    // ISSUE(slice T, T=0..63): one async load; lane l covers code row
    // (T>>5)*64+l, bytes [(T&31)*16,+16). Dest linear: ringbuf T&3 + lane*16.
#define ISSUE(T) { \
    const char* _src = cwb + (((T) >> 5) << 15) + ((size_t)l << 9) + (((T) & 31) << 4); \
    gload16(_src, csw + (((T) & 3) << 10)); }

    // prologue: pair 0 (slices 0,1) into bufs 0,1
    ISSUE(0);
    ISSUE(1);
    // c2 stage: wave's 128 values (lanes 0..31, one float4 each)
    if (l < 32) {
        float4 cv = *(const float4*)(c2 + half * 512 + w * 128 + l * 4);
        *(float4*)&ccl[w][l * 4] = cv;
    }

    // stage X tile (fp32 residual), coalesced float4
    #pragma unroll
    for (int it = 0; it < 8; ++it) {
        int e = (it * 256 + tid) * 4;
        int p = e >> 7, d = e & 127;
        *(float4*)&xs[p][d] = *(const float4*)(resid + (size_t)(pbase + p) * D + d);
    }
    __syncthreads();

    // xx per point: numpy pairwise n=128 (8-accumulator pattern); store in pad
    if (tid < TM) {
        float r8[8];
        #pragma unroll
        for (int j = 0; j < 8; ++j) r8[j] = __fmul_rn(xs[tid][j], xs[tid][j]);
        for (int i = 8; i < 128; i += 8)
            #pragma unroll
            for (int j = 0; j < 8; ++j)
                r8[j] = __fadd_rn(r8[j], __fmul_rn(xs[tid][i + j], xs[tid][i + j]));
        float s01 = __fadd_rn(r8[0], r8[1]);
        float s23 = __fadd_rn(r8[2], r8[3]);
        float s45 = __fadd_rn(r8[4], r8[5]);
        float s67 = __fadd_rn(r8[6], r8[7]);
        xs[tid][128] = __fadd_rn(__fadd_rn(s01, s23), __fadd_rn(s45, s67));
    }
    __syncthreads();

    float xxr[8];
    #pragma unroll
    for (int i = 0; i < 8; ++i) xxr[i] = xs[pl + 8 * i][128];

    float acc[8][8];
    #pragma unroll
    for (int i = 0; i < 8; ++i)
        #pragma unroll
        for (int j = 0; j < 8; ++j) acc[i][j] = 0.0f;
    float best[8]; int bidx[8];
    #pragma unroll
    for (int i = 0; i < 8; ++i) { best[i] = 3.4e38f; bidx[i] = 0; }

    #pragma unroll 1
    for (int P = 0; P < 32; ++P) {           // pair-step: slices 2P, 2P+1 (8 dims)
        if (P < 31) {
            ISSUE(2 * P + 2);                // next pair into the other buf pair
            ISSUE(2 * P + 3);
            asm volatile("s_waitcnt vmcnt(2)" ::: "memory");   // pair P arrived
        } else {
            asm volatile("s_waitcnt vmcnt(0)" ::: "memory");
        }
        int gA = 2 * P;
        const char* cbufA = csw + ((gA & 3) << 10) + (cl << 4);      // slice A
        const char* cbufB = csw + (((gA + 1) & 3) << 10) + (cl << 4);// slice B
        const char* xrowA = xsb + pl * 528 + ((gA & 31) << 4);       // dims 4sA..
        const char* xrowB = xrowA + 16;                              // dims 4sA+4..
        #pragma unroll
        for (int jh = 0; jh < 2; ++jh) {     // 4-code halves: bounded cf pressure
            float4 cA[4], cB[4];
            #pragma unroll
            for (int jc = 0; jc < 4; ++jc) {
                cA[jc] = *(const float4*)(cbufA + ((jh * 4 + jc) << 7));
                cB[jc] = *(const float4*)(cbufB + ((jh * 4 + jc) << 7));
            }
            #pragma unroll
            for (int i = 0; i < 8; ++i) {
                float4 xA = *(const float4*)(xrowA + i * 4224);
                float4 xB = *(const float4*)(xrowB + i * 4224);
                #pragma unroll
                for (int jc = 0; jc < 4; ++jc) {
                    int jj = jh * 4 + jc;
                    float a = acc[i][jj];    // ONE acc touch per 8 dims
                    a = __fmaf_rn(xA.x, cA[jc].x, a);
                    a = __fmaf_rn(xA.y, cA[jc].y, a);
                    a = __fmaf_rn(xA.z, cA[jc].z, a);
                    a = __fmaf_rn(xA.w, cA[jc].w, a);
                    a = __fmaf_rn(xB.x, cB[jc].x, a);
                    a = __fmaf_rn(xB.y, cB[jc].y, a);
                    a = __fmaf_rn(xB.z, cB[jc].z, a);
                    a = __fmaf_rn(xB.w, cB[jc].w, a);
                    acc[i][jj] = a;
                }
            }
        }
        if ((P & 15) == 15) {                // end of 64-code chunk: fold
            int c = P >> 4;
            #pragma unroll
            for (int j = 0; j < 8; ++j) {
                float cc = ccl[w][(c << 6) + cl + (j << 3)];
                int k = half * 512 + (w << 7) + (c << 6) + cl + (j << 3);
                #pragma unroll
                for (int i = 0; i < 8; ++i) {
                    float t1  = __fadd_rn(xxr[i], __fmul_rn(-2.0f, acc[i][j]));
                    float dsc = __fadd_rn(t1, cc);
                    if (dsc < best[i]) { best[i] = dsc; bidx[i] = k; }  // k asc
                    acc[i][j] = 0.0f;
                }
            }
        }
    }

    // cross-lane (cl bits 3..5) lexicographic argmin reduce, then cross-wave
    #pragma unroll
    for (int i = 0; i < 8; ++i) {
        float b = best[i]; int bi = bidx[i];
        #pragma unroll
        for (int off = 8; off < 64; off <<= 1) {
            float b2 = __shfl_xor(b, off, 64);
            int  bi2 = __shfl_xor(bi, off, 64);
            if (b2 < b || (b2 == b && bi2 < bi)) { b = b2; bi = bi2; }
        }
        if (cl == 0) { redS[w][pl + 8 * i] = b; redI[w][pl + 8 * i] = bi; }
    }
    __syncthreads();
    if (tid < TM) {
        float b = redS[0][tid]; int bi = redI[0][tid];
        #pragma unroll
        for (int ww = 1; ww < 4; ++ww) {
            float b2 = redS[ww][tid]; int bi2 = redI[ww][tid];
            if (b2 < b || (b2 == b && bi2 < bi)) { b = b2; bi = bi2; }
        }
        pbest[half * NPTS + pbase + tid] = b;
        pidx [half * NPTS + pbase + tid] = bi;
    }
#undef ISSUE
}

// ---------------- fused merge + residual/quant update (fp32, exact np order) ----
__global__ void k_update(const float* __restrict__ cb,
                         const float* __restrict__ pbest,
                         const int* __restrict__ pidx,
                         int* __restrict__ idx,
                         float* __restrict__ resid, float* __restrict__ quant) {
    int gid = blockIdx.x * blockDim.x + threadIdx.x;   // NPTS*32
    int n = gid >> 5, d4 = (gid & 31) * 4;
    float a = pbest[n], b = pbest[NPTS + n];
    int ia = pidx[n], ib = pidx[NPTS + n];
    int k = (b < a) ? ib : ia;          // tie -> half 0 (lower k): first-min
    if ((gid & 31) == 0) idx[n] = k;
    float4 c = *(const float4*)(cb + (size_t)k * D + d4);
    size_t o = (size_t)n * D + d4;
    float4 r = *(const float4*)(resid + o);
    float4 q = *(const float4*)(quant + o);
    r.x = __fsub_rn(r.x, c.x); r.y = __fsub_rn(r.y, c.y);
    r.z = __fsub_rn(r.z, c.z); r.w = __fsub_rn(r.w, c.w);
    q.x = __fadd_rn(q.x, c.x); q.y = __fadd_rn(q.y, c.y);
    q.z = __fadd_rn(q.z, c.z); q.w = __fadd_rn(q.w, c.w);
    *(float4*)(resid + o) = r;
    *(float4*)(quant + o) = q;
}

// ---------------- out0 = fl(z + fl(q - z)) transposed; commitment partial ----------------
__global__ __launch_bounds__(256) void k_out0(const float* __restrict__ z,
                                              const float* __restrict__ quant,
                                              float* __restrict__ out0,
                                              double* __restrict__ csum) {
    __shared__ float xt[64][129];
    __shared__ double wsum[4];
    int b = blockIdx.x >> 6, st = blockIdx.x & 63;
    int s0 = st * 64;
    for (int it = 0; it < 8; ++it) {
        int flat = it * 256 + threadIdx.x;
        int sl = flat >> 5, dq = (flat & 31) * 4;
        float4 q = *(const float4*)(quant + (size_t)(b * SLEN + s0 + sl) * D + dq);
        xt[sl][dq] = q.x; xt[sl][dq + 1] = q.y;
        xt[sl][dq + 2] = q.z; xt[sl][dq + 3] = q.w;
    }
    __syncthreads();
    double v = 0.0;
    for (int it = 0; it < 32; ++it) {
        int flat = it * 256 + threadIdx.x;
        int d = flat >> 6, sl = flat & 63;
        size_t o = ((size_t)(b * D + d)) * SLEN + s0 + sl;
        float zz = z[o], qq = xt[sl][d];
        out0[o] = __fadd_rn(zz, __fsub_rn(qq, zz));
        float e = __fsub_rn(zz, qq);
        v += (double)e * (double)e;
    }
    for (int off = 32; off > 0; off >>= 1) v += __shfl_down(v, off, 64);
    int lane = threadIdx.x & 63, wv = threadIdx.x >> 6;
    if (lane == 0) wsum[wv] = v;
    __syncthreads();
    if (threadIdx.x == 0) {
        double tsum = wsum[0] + wsum[1] + wsum[2] + wsum[3];
        atomicAdd(csum, tsum);
    }
}

// ---------------- indices output as float ----------------
__global__ void k_outidx(const int* __restrict__ idx, float* __restrict__ out1) {
    int o = blockIdx.x * blockDim.x + threadIdx.x;   // NPTS*NQ
    int q = o & 7, n = o >> 3;
    out1[o] = (float)idx[q * NPTS + n];
}

// ---------------- histogram ----------------
__global__ void k_hist(const int* __restrict__ idx, int* __restrict__ hist) {
    int o = blockIdx.x * blockDim.x + threadIdx.x;   // NQ*NPTS (layout [q][n])
    int q = o >> 15;
    atomicAdd(&hist[q * KCODES + idx[o]], 1);
}

// ---------------- final scalars ----------------
__global__ __launch_bounds__(256) void k_final(const int* __restrict__ hist,
                                               const double* __restrict__ csum,
                                               float* __restrict__ outs) {
    __shared__ double sh[256];
    double perp = 0.0;
    for (int q = 0; q < NQ; ++q) {
        double h = 0.0;
        for (int k = threadIdx.x; k < KCODES; k += 256) {
            double p = (double)hist[q * KCODES + k] / (double)NPTS;
            h -= p * log(p + 1e-10);
        }
        sh[threadIdx.x] = h; __syncthreads();
        for (int off = 128; off > 0; off >>= 1) {
            if (threadIdx.x < off) sh[threadIdx.x] += sh[threadIdx.x + off];
            __syncthreads();
        }
        if (threadIdx.x == 0) perp += exp(sh[0]);
        __syncthreads();
    }
    if (threadIdx.x == 0) {
        outs[0] = (float)(*csum / (double)((size_t)NPTS * D));
        outs[1] = (float)(perp / (double)NQ);
    }
}

extern "C" void kernel_launch(void* const* d_in, const int* in_sizes, int n_in,
                              void* d_out, int out_size, void* d_ws, size_t ws_size,
                              hipStream_t stream) {
    const float* z  = (const float*)d_in[0];
    const float* cb = (const float*)d_in[1];
    float* out0 = (float*)d_out;                 // 4,194,304 floats [B,D,S]
    float* out1 = out0 + 4194304;                // 262,144 floats  [B,S,Q]
    float* outs = out1 + 262144;                 // 2 scalars

    char* w = (char*)d_ws;
    float* resid  = (float*)w;                           // 16,777,216 B
    float* quant  = (float*)(w + 16777216);              // 16,777,216 B
    int*   idx    = (int*)(w + 33554432);                //  1,048,576 B
    int*   hist   = (int*)(w + 34603008);                //     32,768 B
    double* csum  = (double*)(w + 34635776);             //         64 B
    float* c2f    = (float*)(w + 34635840);              //     32,768 B
    float* pbest  = (float*)(w + 34668608);              //    262,144 B
    int*   pidx   = (int*)(w + 34930752);                //    262,144 B

    k_zero<<<32, 256, 0, stream>>>(hist, csum);
    k_c2<<<32, 256, 0, stream>>>(cb, c2f);
    k_init<<<512, 256, 0, stream>>>(z, resid, quant);

    for (int q = 0; q < NQ; ++q) {
        const float* cbq = cb + (size_t)q * KCODES * D;
        k_argmin<<<2 * NPTS / TM, 256, 0, stream>>>(cbq, c2f + q * KCODES, resid,
                                                    pbest, pidx);
        k_update<<<NPTS * 32 / 256, 256, 0, stream>>>(cbq, pbest, pidx,
                                                      idx + q * NPTS, resid, quant);
    }

    k_out0<<<512, 256, 0, stream>>>(z, quant, out0, csum);
    k_outidx<<<NPTS * NQ / 256, 256, 0, stream>>>(idx, out1);
    k_hist<<<NPTS * NQ / 256, 256, 0, stream>>>(idx, hist);
    k_final<<<1, 256, 0, stream>>>(hist, csum, outs);
}

// Round 10
// 1079.826 us; speedup vs baseline: 1.1294x; 1.1294x over previous
//
#include <hip/hip_runtime.h>
#include <math.h>
#include <stdint.h>

#define D       128
#define KCODES  1024
#define NQ      8
#define BATCH   8
#define SLEN    4096
#define NPTS    (BATCH*SLEN)     /* 32768 */
#define TM      64               /* points per argmin unit */

// async global->LDS, 16B per lane (wave-uniform LDS base + lane*16)
typedef __attribute__((address_space(1))) const void GV;
typedef __attribute__((address_space(3))) void LV;
__device__ __forceinline__ void gload16(const void* g, void* l) {
    __builtin_amdgcn_global_load_lds((GV*)g, (LV*)l, 16, 0, 0);
}

// ---------------- zero scratch ----------------
__global__ void k_zero(int* hist, double* csum) {
    int t = blockIdx.x * blockDim.x + threadIdx.x;
    if (t < NQ * KCODES) hist[t] = 0;
    if (t == 0) *csum = 0.0;
}

// ---------------- codebook norms: numpy pairwise fp32 ----------------
__global__ void k_c2(const float* __restrict__ cbs, float* __restrict__ c2f) {
    int i = blockIdx.x * blockDim.x + threadIdx.x;   // 0..8191
    const float* row = cbs + (size_t)i * D;
    float r8[8];
    #pragma unroll
    for (int j = 0; j < 8; ++j) r8[j] = __fmul_rn(row[j], row[j]);
    for (int d = 8; d < 128; d += 8)
        #pragma unroll
        for (int j = 0; j < 8; ++j)
            r8[j] = __fadd_rn(r8[j], __fmul_rn(row[d + j], row[d + j]));
    float s01 = __fadd_rn(r8[0], r8[1]);
    float s23 = __fadd_rn(r8[2], r8[3]);
    float s45 = __fadd_rn(r8[4], r8[5]);
    float s67 = __fadd_rn(r8[6], r8[7]);
    c2f[i] = __fadd_rn(__fadd_rn(s01, s23), __fadd_rn(s45, s67));
}

// ---------------- init: z [B,D,S] -> resid fp32 [n][d]; quant = 0 ----------------
__global__ __launch_bounds__(256) void k_init(const float* __restrict__ z,
                                              float* __restrict__ resid,
                                              float* __restrict__ quant) {
    __shared__ float xt[64][129];
    int b = blockIdx.x >> 6, st = blockIdx.x & 63;
    int s0 = st * 64;
    for (int it = 0; it < 32; ++it) {
        int flat = it * 256 + threadIdx.x;
        int d = flat >> 6, sl = flat & 63;
        xt[sl][d] = z[((size_t)(b * D + d)) * SLEN + s0 + sl];
    }
    __syncthreads();
    for (int it = 0; it < 8; ++it) {
        int flat = it * 256 + threadIdx.x;
        int sl = flat >> 5, dq = (flat & 31) * 4;
        size_t o = (size_t)(b * SLEN + s0 + sl) * D + dq;
        float4 r;
        r.x = xt[sl][dq]; r.y = xt[sl][dq + 1];
        r.z = xt[sl][dq + 2]; r.w = xt[sl][dq + 3];
        *(float4*)(resid + o) = r;
        float4 zz; zz.x = zz.y = zz.z = zz.w = 0.0f;
        *(float4*)(quant + o) = zz;
    }
}

// ---------------- fp32-emulated argmin (matches numpy/BLAS rounding) ----------------
// r10: model from r7-r9: dur ~= max(VALU_wall, LDS_wall) + ~35us gap.
//   r8: VALU 104 (copy tax 50%), LDS 82 -> 140.  r9: VALU 89.5 (tax 25%)
//   but LDS 123 (48 reads/512 FMA) -> 157.  Fix: 8-dim acc touches (tax
//   25%) at r8's read ratio (32 b128/512 FMA).
// Structure: 8-dim slices; cs buf = [64 codes][8 dims] = 2KB, dbuf, 2 DMAs
// per slice, vmcnt(2) gate. Per step: stage cf for all 8 codes (16 b128,
// 64 regs), then per point i: read x pair (2 b128, transient), RMW each
// acc[i][j] via temp across 8 dims (2 AGPR copies / 8 FMAs).
// xx re-read from xs pad at fold (saves 8 regs). __launch_bounds__(256,2)
// = r8-proven arch cap 128 (guard; excess -> AGPR, not scratch).
// Grid 1024 = 512 pblk x 2 code-halves; wave w owns 128 codes
// [half*512+w*128,+128) in 2 chunks of 64; pl=l&7, cl=l>>3.
// cf reads 2-way bank-aliased (free, m136); x reads broadcast (conflict-
// free); LDS 54,272 B -> 3 blocks/CU.
// Exact fp32 semantics (r2..r9-verified): per (point,code) single FMA
// chain dims 0..127 ascending (8-dim slices ascending, dims ascending
// inside); score fl(fl(xx-2*acc)+cc); first-min (strict <, k ascending;
// lex (score,k) reduce; cross-half merge tie -> lower half).
__global__ __launch_bounds__(256, 2) void k_argmin(const float* __restrict__ cb,
                                                   const float* __restrict__ c2,
                                                   const float* __restrict__ resid,
                                                   float* __restrict__ pbest,
                                                   int* __restrict__ pidx) {
    __shared__ __align__(16) float xs[TM][132];       // 33,792 B (xx in col 128)
    __shared__ __align__(16) float cs[4][2][512];     // 16,384 B: [wave][buf][64c x 8d]
    __shared__ __align__(16) float ccl[4][128];       //  2,048 B: per-wave c2
    __shared__ float redS[4][TM];                     //  1,024 B
    __shared__ int   redI[4][TM];                     //  1,024 B

    int tid = threadIdx.x;
    int u = blockIdx.x;
    int pblk = u >> 1, half = u & 1;
    int pbase = pblk * TM;
    int l = tid & 63, w = tid >> 6;
    int pl = l & 7, cl = l >> 3;

    // wave's 128 code rows (512 B each)
    const char* cwb = (const char*)cb + ((size_t)(half * 512 + w * 128) << 9);
    char* csw = (char*)&cs[w][0][0];
    const char* xsb = (const char*)&xs[0][0];

    // per-lane DMA source offset inside a (chunk,slice,g) unit:
    // dest byte i = g*1024 + l*16 -> code g*32+(l>>1), row-half (l&1)
    int lanoff = ((l >> 1) << 9) + ((l & 1) << 4);

    // ISSUE(slice T, T=0..31): 2 async loads into ring buf T&1 (2KB).
    // chunk c=T>>4 (+32KB), slice s=T&15 (row bytes s*32).
#define ISSUE(T) { \
    const char* _src = cwb + (((T) >> 4) << 15) + (((T) & 15) << 5) + lanoff; \
    char* _dst = csw + (((T) & 1) << 11); \
    gload16(_src,             _dst); \
    gload16(_src + (1 << 14), _dst + 1024); }

    // prologue: slice 0 into buf 0
    ISSUE(0);
    // c2 stage: wave's 128 values (lanes 0..31, one float4 each)
    if (l < 32) {
        float4 cv = *(const float4*)(c2 + half * 512 + w * 128 + l * 4);
        *(float4*)&ccl[w][l * 4] = cv;
    }

    // stage X tile (fp32 residual), coalesced float4
    #pragma unroll
    for (int it = 0; it < 8; ++it) {
        int e = (it * 256 + tid) * 4;
        int p = e >> 7, d = e & 127;
        *(float4*)&xs[p][d] = *(const float4*)(resid + (size_t)(pbase + p) * D + d);
    }
    __syncthreads();

    // xx per point: numpy pairwise n=128 (8-accumulator pattern); store in pad
    if (tid < TM) {
        float r8[8];
        #pragma unroll
        for (int j = 0; j < 8; ++j) r8[j] = __fmul_rn(xs[tid][j], xs[tid][j]);
        for (int i = 8; i < 128; i += 8)
            #pragma unroll
            for (int j = 0; j < 8; ++j)
                r8[j] = __fadd_rn(r8[j], __fmul_rn(xs[tid][i + j], xs[tid][i + j]));
        float s01 = __fadd_rn(r8[0], r8[1]);
        float s23 = __fadd_rn(r8[2], r8[3]);
        float s45 = __fadd_rn(r8[4], r8[5]);
        float s67 = __fadd_rn(r8[6], r8[7]);
        xs[tid][128] = __fadd_rn(__fadd_rn(s01, s23), __fadd_rn(s45, s67));
    }
    __syncthreads();

    float acc[8][8];
    #pragma unroll
    for (int i = 0; i < 8; ++i)
        #pragma unroll
        for (int j = 0; j < 8; ++j) acc[i][j] = 0.0f;
    float best[8]; int bidx[8];
    #pragma unroll
    for (int i = 0; i < 8; ++i) { best[i] = 3.4e38f; bidx[i] = 0; }

    #pragma unroll 1
    for (int t = 0; t < 32; ++t) {           // 8-dim slice; chunk c=t>>4, s=t&15
        if (t < 31) {
            ISSUE(t + 1);
            asm volatile("s_waitcnt vmcnt(2)" ::: "memory");   // slice t arrived
        } else {
            asm volatile("s_waitcnt vmcnt(0)" ::: "memory");
        }
        const char* cbuf = csw + ((t & 1) << 11) + (cl << 5);  // code row cl (32B)
        const char* xrow = xsb + pl * 528 + ((t & 15) << 5);   // dims 8s..8s+7
        // stage cf for all 8 codes (code row cl+8j at +j*256B)
        float4 cfa[8], cfb[8];
        #pragma unroll
        for (int j = 0; j < 8; ++j) {
            cfa[j] = *(const float4*)(cbuf + (j << 8));
            cfb[j] = *(const float4*)(cbuf + (j << 8) + 16);
        }
        #pragma unroll
        for (int i = 0; i < 8; ++i) {
            float4 xA = *(const float4*)(xrow + i * 4224);
            float4 xB = *(const float4*)(xrow + i * 4224 + 16);
            #pragma unroll
            for (int j = 0; j < 8; ++j) {
                float a = acc[i][j];         // ONE acc touch per 8 dims
                a = __fmaf_rn(xA.x, cfa[j].x, a);
                a = __fmaf_rn(xA.y, cfa[j].y, a);
                a = __fmaf_rn(xA.z, cfa[j].z, a);
                a = __fmaf_rn(xA.w, cfa[j].w, a);
                a = __fmaf_rn(xB.x, cfb[j].x, a);
                a = __fmaf_rn(xB.y, cfb[j].y, a);
                a = __fmaf_rn(xB.z, cfb[j].z, a);
                a = __fmaf_rn(xB.w, cfb[j].w, a);
                acc[i][j] = a;
            }
        }
        if ((t & 15) == 15) {                // end of 64-code chunk: fold
            int c = t >> 4;
            #pragma unroll
            for (int i = 0; i < 8; ++i) {
                float xxv = xs[pl + 8 * i][128];
                #pragma unroll
                for (int j = 0; j < 8; ++j) {   // ascending k for this point
                    float cc = ccl[w][(c << 6) + cl + (j << 3)];
                    int k = half * 512 + (w << 7) + (c << 6) + cl + (j << 3);
                    float t1  = __fadd_rn(xxv, __fmul_rn(-2.0f, acc[i][j]));
                    float dsc = __fadd_rn(t1, cc);
                    if (dsc < best[i]) { best[i] = dsc; bidx[i] = k; }
                    acc[i][j] = 0.0f;
                }
            }
        }
    }

    // cross-lane (cl bits 3..5) lexicographic argmin reduce, then cross-wave
    #pragma unroll
    for (int i = 0; i < 8; ++i) {
        float b = best[i]; int bi = bidx[i];
        #pragma unroll
        for (int off = 8; off < 64; off <<= 1) {
            float b2 = __shfl_xor(b, off, 64);
            int  bi2 = __shfl_xor(bi, off, 64);
            if (b2 < b || (b2 == b && bi2 < bi)) { b = b2; bi = bi2; }
        }
        if (cl == 0) { redS[w][pl + 8 * i] = b; redI[w][pl + 8 * i] = bi; }
    }
    __syncthreads();
    if (tid < TM) {
        float b = redS[0][tid]; int bi = redI[0][tid];
        #pragma unroll
        for (int ww = 1; ww < 4; ++ww) {
            float b2 = redS[ww][tid]; int bi2 = redI[ww][tid];
            if (b2 < b || (b2 == b && bi2 < bi)) { b = b2; bi = bi2; }
        }
        pbest[half * NPTS + pbase + tid] = b;
        pidx [half * NPTS + pbase + tid] = bi;
    }
#undef ISSUE
}

// ---------------- fused merge + residual/quant update (fp32, exact np order) ----
__global__ void k_update(const float* __restrict__ cb,
                         const float* __restrict__ pbest,
                         const int* __restrict__ pidx,
                         int* __restrict__ idx,
                         float* __restrict__ resid, float* __restrict__ quant) {
    int gid = blockIdx.x * blockDim.x + threadIdx.x;   // NPTS*32
    int n = gid >> 5, d4 = (gid & 31) * 4;
    float a = pbest[n], b = pbest[NPTS + n];
    int ia = pidx[n], ib = pidx[NPTS + n];
    int k = (b < a) ? ib : ia;          // tie -> half 0 (lower k): first-min
    if ((gid & 31) == 0) idx[n] = k;
    float4 c = *(const float4*)(cb + (size_t)k * D + d4);
    size_t o = (size_t)n * D + d4;
    float4 r = *(const float4*)(resid + o);
    float4 q = *(const float4*)(quant + o);
    r.x = __fsub_rn(r.x, c.x); r.y = __fsub_rn(r.y, c.y);
    r.z = __fsub_rn(r.z, c.z); r.w = __fsub_rn(r.w, c.w);
    q.x = __fadd_rn(q.x, c.x); q.y = __fadd_rn(q.y, c.y);
    q.z = __fadd_rn(q.z, c.z); q.w = __fadd_rn(q.w, c.w);
    *(float4*)(resid + o) = r;
    *(float4*)(quant + o) = q;
}

// ---------------- out0 = fl(z + fl(q - z)) transposed; commitment partial ----------------
__global__ __launch_bounds__(256) void k_out0(const float* __restrict__ z,
                                              const float* __restrict__ quant,
                                              float* __restrict__ out0,
                                              double* __restrict__ csum) {
    __shared__ float xt[64][129];
    __shared__ double wsum[4];
    int b = blockIdx.x >> 6, st = blockIdx.x & 63;
    int s0 = st * 64;
    for (int it = 0; it < 8; ++it) {
        int flat = it * 256 + threadIdx.x;
        int sl = flat >> 5, dq = (flat & 31) * 4;
        float4 q = *(const float4*)(quant + (size_t)(b * SLEN + s0 + sl) * D + dq);
        xt[sl][dq] = q.x; xt[sl][dq + 1] = q.y;
        xt[sl][dq + 2] = q.z; xt[sl][dq + 3] = q.w;
    }
    __syncthreads();
    double v = 0.0;
    for (int it = 0; it < 32; ++it) {
        int flat = it * 256 + threadIdx.x;
        int d = flat >> 6, sl = flat & 63;
        size_t o = ((size_t)(b * D + d)) * SLEN + s0 + sl;
        float zz = z[o], qq = xt[sl][d];
        out0[o] = __fadd_rn(zz, __fsub_rn(qq, zz));
        float e = __fsub_rn(zz, qq);
        v += (double)e * (double)e;
    }
    for (int off = 32; off > 0; off >>= 1) v += __shfl_down(v, off, 64);
    int lane = threadIdx.x & 63, wv = threadIdx.x >> 6;
    if (lane == 0) wsum[wv] = v;
    __syncthreads();
    if (threadIdx.x == 0) {
        double tsum = wsum[0] + wsum[1] + wsum[2] + wsum[3];
        atomicAdd(csum, tsum);
    }
}

// ---------------- indices output as float ----------------
__global__ void k_outidx(const int* __restrict__ idx, float* __restrict__ out1) {
    int o = blockIdx.x * blockDim.x + threadIdx.x;   // NPTS*NQ
    int q = o & 7, n = o >> 3;
    out1[o] = (float)idx[q * NPTS + n];
}

// ---------------- histogram ----------------
__global__ void k_hist(const int* __restrict__ idx, int* __restrict__ hist) {
    int o = blockIdx.x * blockDim.x + threadIdx.x;   // NQ*NPTS (layout [q][n])
    int q = o >> 15;
    atomicAdd(&hist[q * KCODES + idx[o]], 1);
}

// ---------------- final scalars ----------------
__global__ __launch_bounds__(256) void k_final(const int* __restrict__ hist,
                                               const double* __restrict__ csum,
                                               float* __restrict__ outs) {
    __shared__ double sh[256];
    double perp = 0.0;
    for (int q = 0; q < NQ; ++q) {
        double h = 0.0;
        for (int k = threadIdx.x; k < KCODES; k += 256) {
            double p = (double)hist[q * KCODES + k] / (double)NPTS;
            h -= p * log(p + 1e-10);
        }
        sh[threadIdx.x] = h; __syncthreads();
        for (int off = 128; off > 0; off >>= 1) {
            if (threadIdx.x < off) sh[threadIdx.x] += sh[threadIdx.x + off];
            __syncthreads();
        }
        if (threadIdx.x == 0) perp += exp(sh[0]);
        __syncthreads();
    }
    if (threadIdx.x == 0) {
        outs[0] = (float)(*csum / (double)((size_t)NPTS * D));
        outs[1] = (float)(perp / (double)NQ);
    }
}

extern "C" void kernel_launch(void* const* d_in, const int* in_sizes, int n_in,
                              void* d_out, int out_size, void* d_ws, size_t ws_size,
                              hipStream_t stream) {
    const float* z  = (const float*)d_in[0];
    const float* cb = (const float*)d_in[1];
    float* out0 = (float*)d_out;                 // 4,194,304 floats [B,D,S]
    float* out1 = out0 + 4194304;                // 262,144 floats  [B,S,Q]
    float* outs = out1 + 262144;                 // 2 scalars

    char* w = (char*)d_ws;
    float* resid  = (float*)w;                           // 16,777,216 B
    float* quant  = (float*)(w + 16777216);              // 16,777,216 B
    int*   idx    = (int*)(w + 33554432);                //  1,048,576 B
    int*   hist   = (int*)(w + 34603008);                //     32,768 B
    double* csum  = (double*)(w + 34635776);             //         64 B
    float* c2f    = (float*)(w + 34635840);              //     32,768 B
    float* pbest  = (float*)(w + 34668608);              //    262,144 B
    int*   pidx   = (int*)(w + 34930752);                //    262,144 B

    k_zero<<<32, 256, 0, stream>>>(hist, csum);
    k_c2<<<32, 256, 0, stream>>>(cb, c2f);
    k_init<<<512, 256, 0, stream>>>(z, resid, quant);

    for (int q = 0; q < NQ; ++q) {
        const float* cbq = cb + (size_t)q * KCODES * D;
        k_argmin<<<2 * NPTS / TM, 256, 0, stream>>>(cbq, c2f + q * KCODES, resid,
                                                    pbest, pidx);
        k_update<<<NPTS * 32 / 256, 256, 0, stream>>>(cbq, pbest, pidx,
                                                      idx + q * NPTS, resid, quant);
    }

    k_out0<<<512, 256, 0, stream>>>(z, quant, out0, csum);
    k_outidx<<<NPTS * NQ / 256, 256, 0, stream>>>(idx, out1);
    k_hist<<<NPTS * NQ / 256, 256, 0, stream>>>(idx, hist);
    k_final<<<1, 256, 0, stream>>>(hist, csum, outs);
}

// Round 12
// 1017.508 us; speedup vs baseline: 1.1986x; 1.0612x over previous
//
#include <hip/hip_runtime.h>
#include <math.h>
#include <stdint.h>

#define D       128
#define KCODES  1024
#define NQ      8
#define BATCH   8
#define SLEN    4096
#define NPTS    (BATCH*SLEN)     /* 32768 */
#define TM      64               /* points per argmin unit */

typedef __attribute__((ext_vector_type(2))) float f32x2;

// async global->LDS, 16B per lane (wave-uniform LDS base + lane*16)
typedef __attribute__((address_space(1))) const void GV;
typedef __attribute__((address_space(3))) void LV;
__device__ __forceinline__ void gload16(const void* g, void* l) {
    __builtin_amdgcn_global_load_lds((GV*)g, (LV*)l, 16, 0, 0);
}

// packed fp32 FMA, C scalar broadcast from a 64-bit pair CP:
//  _LO: both halves read CP.lo   (op_sel src1=0, op_sel_hi src1=0)
//  _HI: both halves read CP.hi   (op_sel src1=1, op_sel_hi src1=1)
// X/A halves: lo op reads .lo, hi op reads .hi (defaults for src0/src2).
// Each half is an independent IEEE-rn fp32 FMA -> bit-exact per-chain.
#define PKFMA_LO(A, X, CP) \
    asm("v_pk_fma_f32 %0, %1, %2, %0 op_sel_hi:[1,0,1]" \
        : "+v"(A) : "v"(X), "v"(CP))
#define PKFMA_HI(A, X, CP) \
    asm("v_pk_fma_f32 %0, %1, %2, %0 op_sel:[0,1,0] op_sel_hi:[1,1,1]" \
        : "+v"(A) : "v"(X), "v"(CP))

// ---------------- zero scratch ----------------
__global__ void k_zero(int* hist, double* csum) {
    int t = blockIdx.x * blockDim.x + threadIdx.x;
    if (t < NQ * KCODES) hist[t] = 0;
    if (t == 0) *csum = 0.0;
}

// ---------------- codebook norms: numpy pairwise fp32 ----------------
__global__ void k_c2(const float* __restrict__ cbs, float* __restrict__ c2f) {
    int i = blockIdx.x * blockDim.x + threadIdx.x;   // 0..8191
    const float* row = cbs + (size_t)i * D;
    float r8[8];
    #pragma unroll
    for (int j = 0; j < 8; ++j) r8[j] = __fmul_rn(row[j], row[j]);
    for (int d = 8; d < 128; d += 8)
        #pragma unroll
        for (int j = 0; j < 8; ++j)
            r8[j] = __fadd_rn(r8[j], __fmul_rn(row[d + j], row[d + j]));
    float s01 = __fadd_rn(r8[0], r8[1]);
    float s23 = __fadd_rn(r8[2], r8[3]);
    float s45 = __fadd_rn(r8[4], r8[5]);
    float s67 = __fadd_rn(r8[6], r8[7]);
    c2f[i] = __fadd_rn(__fadd_rn(s01, s23), __fadd_rn(s45, s67));
}

// ---------------- init: z [B,D,S] -> resid fp32 [n][d]; quant = 0 ----------------
__global__ __launch_bounds__(256) void k_init(const float* __restrict__ z,
                                              float* __restrict__ resid,
                                              float* __restrict__ quant) {
    __shared__ float xt[64][129];
    int b = blockIdx.x >> 6, st = blockIdx.x & 63;
    int s0 = st * 64;
    for (int it = 0; it < 32; ++it) {
        int flat = it * 256 + threadIdx.x;
        int d = flat >> 6, sl = flat & 63;
        xt[sl][d] = z[((size_t)(b * D + d)) * SLEN + s0 + sl];
    }
    __syncthreads();
    for (int it = 0; it < 8; ++it) {
        int flat = it * 256 + threadIdx.x;
        int sl = flat >> 5, dq = (flat & 31) * 4;
        size_t o = (size_t)(b * SLEN + s0 + sl) * D + dq;
        float4 r;
        r.x = xt[sl][dq]; r.y = xt[sl][dq + 1];
        r.z = xt[sl][dq + 2]; r.w = xt[sl][dq + 3];
        *(float4*)(resid + o) = r;
        float4 zz; zz.x = zz.y = zz.z = zz.w = 0.0f;
        *(float4*)(quant + o) = zz;
    }
}

// ---------------- fp32-emulated argmin (matches numpy/BLAS rounding) ----------------
// r12 = r11 with the VOP3P operand fix: cf passed as even-aligned 64-bit
// PAIRS (float4 -> two f32x2), broadcast via op_sel/op_sel_hi word select
// (r11 compile error: src1 was a single 32-bit vreg -- VOP3P needs pairs).
// Model (r6-r10): dur ~= max(VALU_wall, LDS_wall) + gap. r10: VALU 88,
// LDS 82 -> 133. pk_fma packs the two chains of a POINT PAIR into one
// inst: per step 256 pk + 128 acc copies + misc -> VALU ~50us; LDS
// unchanged (32 b128/step) = 82us binding.
// X tile TRANSPOSED: xst[dim][point] (256B rows; b128 at [d][8pl] = 2 pk
// pairs; 2-way bank alias = free; row 128 = xx). xx computed by wave 0
// from a global re-read with IDENTICAL pairwise-8 arithmetic. Staging
// writes stride-1 b32 (conflict-free). Rest = r10 verbatim (grid 1024 =
// 512 pblk x 2 halves; DMA macro; vmcnt(2); cs 2KB dbuf; fold/lex-reduce;
// merge fused in k_update), point index p = 8*pl + lp.
// Exact fp32 semantics: per (point,code) chain dims 0..127 ascending
// (8-dim slices asc, dims asc inside, each pk half its own chain); score
// fl(fl(xx-2*acc)+cc); first-min (strict <, k asc; lex (score,k) reduce;
// cross-half merge tie -> lower half).
__global__ __launch_bounds__(256, 2) void k_argmin(const float* __restrict__ cb,
                                                   const float* __restrict__ c2,
                                                   const float* __restrict__ resid,
                                                   float* __restrict__ pbest,
                                                   int* __restrict__ pidx) {
    __shared__ __align__(16) float xst[129][64];      // 33,024 B (row 128 = xx)
    __shared__ __align__(16) float cs[4][2][512];     // 16,384 B: [wave][buf][64c x 8d]
    __shared__ __align__(16) float ccl[4][128];       //  2,048 B: per-wave c2
    __shared__ float redS[4][TM];                     //  1,024 B
    __shared__ int   redI[4][TM];                     //  1,024 B

    int tid = threadIdx.x;
    int u = blockIdx.x;
    int pblk = u >> 1, half = u & 1;
    int pbase = pblk * TM;
    int l = tid & 63, w = tid >> 6;
    int pl = l & 7, cl = l >> 3;

    // wave's 128 code rows (512 B each)
    const char* cwb = (const char*)cb + ((size_t)(half * 512 + w * 128) << 9);
    char* csw = (char*)&cs[w][0][0];
    float* xstf = &xst[0][0];

    // per-lane DMA source offset inside a (chunk,slice) unit:
    // dest byte = l*16 -> code l>>1, row-half l&1  (r10-verified mapping)
    int lanoff = ((l >> 1) << 9) + ((l & 1) << 4);

#define ISSUE(T) { \
    const char* _src = cwb + (((T) >> 4) << 15) + (((T) & 15) << 5) + lanoff; \
    char* _dst = csw + (((T) & 1) << 11); \
    gload16(_src,             _dst); \
    gload16(_src + (1 << 14), _dst + 1024); }

    // prologue: slice 0 into buf 0
    ISSUE(0);
    // c2 stage: wave's 128 values (lanes 0..31, one float4 each)
    if (l < 32) {
        float4 cv = *(const float4*)(c2 + half * 512 + w * 128 + l * 4);
        *(float4*)&ccl[w][l * 4] = cv;
    }

    // stage X tile TRANSPOSED: (it,w) owns dim-group g = it*4+w, lane = point
    #pragma unroll
    for (int it = 0; it < 8; ++it) {
        int g = it * 4 + w;                  // dims 4g..4g+3
        float4 v = *(const float4*)(resid + (size_t)(pbase + l) * D + 4 * g);
        xstf[(size_t)(4 * g + 0) * 64 + l] = v.x;
        xstf[(size_t)(4 * g + 1) * 64 + l] = v.y;
        xstf[(size_t)(4 * g + 2) * 64 + l] = v.z;
        xstf[(size_t)(4 * g + 3) * 64 + l] = v.w;
    }
    // xx per point: wave 0, global re-read, numpy pairwise n=128 (exact order)
    if (tid < TM) {
        const float* row = resid + (size_t)(pbase + tid) * D;
        float r8[8];
        #pragma unroll
        for (int j = 0; j < 8; ++j) r8[j] = 0.0f;
        #pragma unroll
        for (int g = 0; g < 32; ++g) {       // dims 4g..4g+3 -> r8[(g&1)*4 ..]
            float4 v = *(const float4*)(row + 4 * g);
            int b = (g & 1) * 4;
            r8[b + 0] = __fadd_rn(r8[b + 0], __fmul_rn(v.x, v.x));
            r8[b + 1] = __fadd_rn(r8[b + 1], __fmul_rn(v.y, v.y));
            r8[b + 2] = __fadd_rn(r8[b + 2], __fmul_rn(v.z, v.z));
            r8[b + 3] = __fadd_rn(r8[b + 3], __fmul_rn(v.w, v.w));
        }
        float s01 = __fadd_rn(r8[0], r8[1]);
        float s23 = __fadd_rn(r8[2], r8[3]);
        float s45 = __fadd_rn(r8[4], r8[5]);
        float s67 = __fadd_rn(r8[6], r8[7]);
        xstf[(size_t)128 * 64 + tid] = __fadd_rn(__fadd_rn(s01, s23),
                                                 __fadd_rn(s45, s67));
    }
    __syncthreads();

    f32x2 accp[4][8];                        // pair m=(pts 8pl+2m,+2m+1) x code j
    #pragma unroll
    for (int m = 0; m < 4; ++m)
        #pragma unroll
        for (int j = 0; j < 8; ++j) { accp[m][j].x = 0.0f; accp[m][j].y = 0.0f; }
    float best[8]; int bidx[8];
    #pragma unroll
    for (int i = 0; i < 8; ++i) { best[i] = 3.4e38f; bidx[i] = 0; }

    #pragma unroll 1
    for (int t = 0; t < 32; ++t) {           // 8-dim slice; chunk c=t>>4, s=t&15
        if (t < 31) {
            ISSUE(t + 1);
            asm volatile("s_waitcnt vmcnt(2)" ::: "memory");   // slice t arrived
        } else {
            asm volatile("s_waitcnt vmcnt(0)" ::: "memory");
        }
        const char* cbuf = csw + ((t & 1) << 11) + (cl << 5);  // code row cl (32B)
        const float* xrow = xstf + (size_t)((t & 15) << 3) * 64 + (pl << 3);
        // stage x pairs: dims 8s+d, points 8pl..8pl+7 as 4 pairs
        f32x2 xA[8], xB[8], xC[8], xD[8];
        #pragma unroll
        for (int d = 0; d < 8; ++d) {
            float4 q = *(const float4*)(xrow + (size_t)d * 64);      // pts 8pl..+3
            float4 r = *(const float4*)(xrow + (size_t)d * 64 + 4);  // pts +4..+7
            const f32x2* qp = (const f32x2*)&q;
            const f32x2* rp = (const f32x2*)&r;
            xA[d] = qp[0]; xB[d] = qp[1]; xC[d] = rp[0]; xD[d] = rp[1];
        }
        #pragma unroll
        for (int j = 0; j < 8; ++j) {
            float4 cfa = *(const float4*)(cbuf + (j << 8));       // dims 8s..+3
            float4 cfb = *(const float4*)(cbuf + (j << 8) + 16);  // dims +4..+7
            const f32x2* ca = (const f32x2*)&cfa;   // ca[0]=(d0,d1) ca[1]=(d2,d3)
            const f32x2* cb2 = (const f32x2*)&cfb;  // cb2[0]=(d4,d5) cb2[1]=(d6,d7)
            f32x2 a0 = accp[0][j], a1 = accp[1][j];
            f32x2 a2 = accp[2][j], a3 = accp[3][j];
            PKFMA_LO(a0, xA[0], ca[0]);  PKFMA_LO(a1, xB[0], ca[0]);
            PKFMA_LO(a2, xC[0], ca[0]);  PKFMA_LO(a3, xD[0], ca[0]);
            PKFMA_HI(a0, xA[1], ca[0]);  PKFMA_HI(a1, xB[1], ca[0]);
            PKFMA_HI(a2, xC[1], ca[0]);  PKFMA_HI(a3, xD[1], ca[0]);
            PKFMA_LO(a0, xA[2], ca[1]);  PKFMA_LO(a1, xB[2], ca[1]);
            PKFMA_LO(a2, xC[2], ca[1]);  PKFMA_LO(a3, xD[2], ca[1]);
            PKFMA_HI(a0, xA[3], ca[1]);  PKFMA_HI(a1, xB[3], ca[1]);
            PKFMA_HI(a2, xC[3], ca[1]);  PKFMA_HI(a3, xD[3], ca[1]);
            PKFMA_LO(a0, xA[4], cb2[0]); PKFMA_LO(a1, xB[4], cb2[0]);
            PKFMA_LO(a2, xC[4], cb2[0]); PKFMA_LO(a3, xD[4], cb2[0]);
            PKFMA_HI(a0, xA[5], cb2[0]); PKFMA_HI(a1, xB[5], cb2[0]);
            PKFMA_HI(a2, xC[5], cb2[0]); PKFMA_HI(a3, xD[5], cb2[0]);
            PKFMA_LO(a0, xA[6], cb2[1]); PKFMA_LO(a1, xB[6], cb2[1]);
            PKFMA_LO(a2, xC[6], cb2[1]); PKFMA_LO(a3, xD[6], cb2[1]);
            PKFMA_HI(a0, xA[7], cb2[1]); PKFMA_HI(a1, xB[7], cb2[1]);
            PKFMA_HI(a2, xC[7], cb2[1]); PKFMA_HI(a3, xD[7], cb2[1]);
            accp[0][j] = a0; accp[1][j] = a1;
            accp[2][j] = a2; accp[3][j] = a3;
        }
        if ((t & 15) == 15) {                // end of 64-code chunk: fold
            int c = t >> 4;
            float xxv[8];
            #pragma unroll
            for (int lp = 0; lp < 8; ++lp)
                xxv[lp] = xstf[(size_t)128 * 64 + 8 * pl + lp];
            #pragma unroll
            for (int j = 0; j < 8; ++j) {    // ascending k per point
                float cc = ccl[w][(c << 6) + cl + (j << 3)];
                int k = half * 512 + (w << 7) + (c << 6) + cl + (j << 3);
                #pragma unroll
                for (int m = 0; m < 4; ++m) {
                    f32x2 av = accp[m][j];
                    float t1, dsc;
                    t1  = __fadd_rn(xxv[2 * m], __fmul_rn(-2.0f, av.x));
                    dsc = __fadd_rn(t1, cc);
                    if (dsc < best[2 * m])     { best[2 * m] = dsc;     bidx[2 * m] = k; }
                    t1  = __fadd_rn(xxv[2 * m + 1], __fmul_rn(-2.0f, av.y));
                    dsc = __fadd_rn(t1, cc);
                    if (dsc < best[2 * m + 1]) { best[2 * m + 1] = dsc; bidx[2 * m + 1] = k; }
                    av.x = 0.0f; av.y = 0.0f;
                    accp[m][j] = av;
                }
            }
        }
    }

    // cross-lane (cl bits 3..5) lexicographic argmin reduce, then cross-wave
    #pragma unroll
    for (int lp = 0; lp < 8; ++lp) {         // point 8*pl + lp
        float b = best[lp]; int bi = bidx[lp];
        #pragma unroll
        for (int off = 8; off < 64; off <<= 1) {
            float b2 = __shfl_xor(b, off, 64);
            int  bi2 = __shfl_xor(bi, off, 64);
            if (b2 < b || (b2 == b && bi2 < bi)) { b = b2; bi = bi2; }
        }
        if (cl == 0) { redS[w][8 * pl + lp] = b; redI[w][8 * pl + lp] = bi; }
    }
    __syncthreads();
    if (tid < TM) {
        float b = redS[0][tid]; int bi = redI[0][tid];
        #pragma unroll
        for (int ww = 1; ww < 4; ++ww) {
            float b2 = redS[ww][tid]; int bi2 = redI[ww][tid];
            if (b2 < b || (b2 == b && bi2 < bi)) { b = b2; bi = bi2; }
        }
        pbest[half * NPTS + pbase + tid] = b;
        pidx [half * NPTS + pbase + tid] = bi;
    }
#undef ISSUE
}

// ---------------- fused merge + residual/quant update (fp32, exact np order) ----
__global__ void k_update(const float* __restrict__ cb,
                         const float* __restrict__ pbest,
                         const int* __restrict__ pidx,
                         int* __restrict__ idx,
                         float* __restrict__ resid, float* __restrict__ quant) {
    int gid = blockIdx.x * blockDim.x + threadIdx.x;   // NPTS*32
    int n = gid >> 5, d4 = (gid & 31) * 4;
    float a = pbest[n], b = pbest[NPTS + n];
    int ia = pidx[n], ib = pidx[NPTS + n];
    int k = (b < a) ? ib : ia;          // tie -> half 0 (lower k): first-min
    if ((gid & 31) == 0) idx[n] = k;
    float4 c = *(const float4*)(cb + (size_t)k * D + d4);
    size_t o = (size_t)n * D + d4;
    float4 r = *(const float4*)(resid + o);
    float4 q = *(const float4*)(quant + o);
    r.x = __fsub_rn(r.x, c.x); r.y = __fsub_rn(r.y, c.y);
    r.z = __fsub_rn(r.z, c.z); r.w = __fsub_rn(r.w, c.w);
    q.x = __fadd_rn(q.x, c.x); q.y = __fadd_rn(q.y, c.y);
    q.z = __fadd_rn(q.z, c.z); q.w = __fadd_rn(q.w, c.w);
    *(float4*)(resid + o) = r;
    *(float4*)(quant + o) = q;
}

// ---------------- out0 = fl(z + fl(q - z)) transposed; commitment partial ----------------
__global__ __launch_bounds__(256) void k_out0(const float* __restrict__ z,
                                              const float* __restrict__ quant,
                                              float* __restrict__ out0,
                                              double* __restrict__ csum) {
    __shared__ float xt[64][129];
    __shared__ double wsum[4];
    int b = blockIdx.x >> 6, st = blockIdx.x & 63;
    int s0 = st * 64;
    for (int it = 0; it < 8; ++it) {
        int flat = it * 256 + threadIdx.x;
        int sl = flat >> 5, dq = (flat & 31) * 4;
        float4 q = *(const float4*)(quant + (size_t)(b * SLEN + s0 + sl) * D + dq);
        xt[sl][dq] = q.x; xt[sl][dq + 1] = q.y;
        xt[sl][dq + 2] = q.z; xt[sl][dq + 3] = q.w;
    }
    __syncthreads();
    double v = 0.0;
    for (int it = 0; it < 32; ++it) {
        int flat = it * 256 + threadIdx.x;
        int d = flat >> 6, sl = flat & 63;
        size_t o = ((size_t)(b * D + d)) * SLEN + s0 + sl;
        float zz = z[o], qq = xt[sl][d];
        out0[o] = __fadd_rn(zz, __fsub_rn(qq, zz));
        float e = __fsub_rn(zz, qq);
        v += (double)e * (double)e;
    }
    for (int off = 32; off > 0; off >>= 1) v += __shfl_down(v, off, 64);
    int lane = threadIdx.x & 63, wv = threadIdx.x >> 6;
    if (lane == 0) wsum[wv] = v;
    __syncthreads();
    if (threadIdx.x == 0) {
        double tsum = wsum[0] + wsum[1] + wsum[2] + wsum[3];
        atomicAdd(csum, tsum);
    }
}

// ---------------- indices output as float ----------------
__global__ void k_outidx(const int* __restrict__ idx, float* __restrict__ out1) {
    int o = blockIdx.x * blockDim.x + threadIdx.x;   // NPTS*NQ
    int q = o & 7, n = o >> 3;
    out1[o] = (float)idx[q * NPTS + n];
}

// ---------------- histogram ----------------
__global__ void k_hist(const int* __restrict__ idx, int* __restrict__ hist) {
    int o = blockIdx.x * blockDim.x + threadIdx.x;   // NQ*NPTS (layout [q][n])
    int q = o >> 15;
    atomicAdd(&hist[q * KCODES + idx[o]], 1);
}

// ---------------- final scalars ----------------
__global__ __launch_bounds__(256) void k_final(const int* __restrict__ hist,
                                               const double* __restrict__ csum,
                                               float* __restrict__ outs) {
    __shared__ double sh[256];
    double perp = 0.0;
    for (int q = 0; q < NQ; ++q) {
        double h = 0.0;
        for (int k = threadIdx.x; k < KCODES; k += 256) {
            double p = (double)hist[q * KCODES + k] / (double)NPTS;
            h -= p * log(p + 1e-10);
        }
        sh[threadIdx.x] = h; __syncthreads();
        for (int off = 128; off > 0; off >>= 1) {
            if (threadIdx.x < off) sh[threadIdx.x] += sh[threadIdx.x + off];
            __syncthreads();
        }
        if (threadIdx.x == 0) perp += exp(sh[0]);
        __syncthreads();
    }
    if (threadIdx.x == 0) {
        outs[0] = (float)(*csum / (double)((size_t)NPTS * D));
        outs[1] = (float)(perp / (double)NQ);
    }
}

extern "C" void kernel_launch(void* const* d_in, const int* in_sizes, int n_in,
                              void* d_out, int out_size, void* d_ws, size_t ws_size,
                              hipStream_t stream) {
    const float* z  = (const float*)d_in[0];
    const float* cb = (const float*)d_in[1];
    float* out0 = (float*)d_out;                 // 4,194,304 floats [B,D,S]
    float* out1 = out0 + 4194304;                // 262,144 floats  [B,S,Q]
    float* outs = out1 + 262144;                 // 2 scalars

    char* w = (char*)d_ws;
    float* resid  = (float*)w;                           // 16,777,216 B
    float* quant  = (float*)(w + 16777216);              // 16,777,216 B
    int*   idx    = (int*)(w + 33554432);                //  1,048,576 B
    int*   hist   = (int*)(w + 34603008);                //     32,768 B
    double* csum  = (double*)(w + 34635776);             //         64 B
    float* c2f    = (float*)(w + 34635840);              //     32,768 B
    float* pbest  = (float*)(w + 34668608);              //    262,144 B
    int*   pidx   = (int*)(w + 34930752);                //    262,144 B

    k_zero<<<32, 256, 0, stream>>>(hist, csum);
    k_c2<<<32, 256, 0, stream>>>(cb, c2f);
    k_init<<<512, 256, 0, stream>>>(z, resid, quant);

    for (int q = 0; q < NQ; ++q) {
        const float* cbq = cb + (size_t)q * KCODES * D;
        k_argmin<<<2 * NPTS / TM, 256, 0, stream>>>(cbq, c2f + q * KCODES, resid,
                                                    pbest, pidx);
        k_update<<<NPTS * 32 / 256, 256, 0, stream>>>(cbq, pbest, pidx,
                                                      idx + q * NPTS, resid, quant);
    }

    k_out0<<<512, 256, 0, stream>>>(z, quant, out0, csum);
    k_outidx<<<NPTS * NQ / 256, 256, 0, stream>>>(idx, out1);
    k_hist<<<NPTS * NQ / 256, 256, 0, stream>>>(idx, hist);
    k_final<<<1, 256, 0, stream>>>(hist, csum, outs);
}